// Round 14
// baseline (127.841 us; speedup 1.0000x reference)
//
#include <hip/hip_runtime.h>

typedef __bf16  bf16x8 __attribute__((ext_vector_type(8)));
typedef float   f32x4  __attribute__((ext_vector_type(4)));
typedef short   short8 __attribute__((ext_vector_type(8)));

static __device__ __forceinline__ unsigned short f2bf(float f) {
  union { float f; unsigned int u; } v; v.f = f;
  unsigned int u = v.u;
  u += 0x7fffu + ((u >> 16) & 1u);   // round-to-nearest-even
  return (unsigned short)(u >> 16);
}

// e2m1 decode: code = sign<<3 | e<<1 | m ; values {0,.5,1,1.5,2,3,4,6} * sign
static __device__ __forceinline__ float fp4_decode(int qc) {
  int e = (qc >> 1) & 3;
  float m = (float)(qc & 1);
  float mag = (e == 0) ? (0.5f * m)
                       : ((2.0f + m) * 0.5f * (float)(1 << (e - 1)));
  return (qc & 8) ? -mag : mag;
}

// Fused prep (R4-proven): blocks [0, nblkW/256) dequant W; rest convert x.
__global__ __launch_bounds__(256) void w4a16_prep(
    const int* __restrict__ wq, const float* __restrict__ wsc,
    short* __restrict__ wout, int nblkW,
    const float* __restrict__ x, short* __restrict__ xb, int n8) {
  const int nbW = nblkW >> 8;
  if ((int)blockIdx.x < nbW) {
    int idx = blockIdx.x * 256 + threadIdx.x;
    if (idx >= nblkW) return;
    float s = wsc[idx];
    const int4* qp = (const int4*)wq + (size_t)idx * 4;
    int4 q0 = qp[0], q1 = qp[1], q2 = qp[2], q3 = qp[3];
    short8 r0, r1;
    r0[0] = (short)f2bf(fp4_decode(q0.x) * s);
    r0[1] = (short)f2bf(fp4_decode(q0.y) * s);
    r0[2] = (short)f2bf(fp4_decode(q0.z) * s);
    r0[3] = (short)f2bf(fp4_decode(q0.w) * s);
    r0[4] = (short)f2bf(fp4_decode(q1.x) * s);
    r0[5] = (short)f2bf(fp4_decode(q1.y) * s);
    r0[6] = (short)f2bf(fp4_decode(q1.z) * s);
    r0[7] = (short)f2bf(fp4_decode(q1.w) * s);
    r1[0] = (short)f2bf(fp4_decode(q2.x) * s);
    r1[1] = (short)f2bf(fp4_decode(q2.y) * s);
    r1[2] = (short)f2bf(fp4_decode(q2.z) * s);
    r1[3] = (short)f2bf(fp4_decode(q2.w) * s);
    r1[4] = (short)f2bf(fp4_decode(q3.x) * s);
    r1[5] = (short)f2bf(fp4_decode(q3.y) * s);
    r1[6] = (short)f2bf(fp4_decode(q3.z) * s);
    r1[7] = (short)f2bf(fp4_decode(q3.w) * s);
    short8* op = (short8*)wout + (size_t)idx * 2;
    op[0] = r0;
    op[1] = r1;
  } else {
    int idx = (blockIdx.x - nbW) * 256 + threadIdx.x;
    if (idx >= n8) return;
    const float4* xp = (const float4*)x + (size_t)idx * 2;
    float4 a = xp[0], b = xp[1];
    short8 r;
    r[0] = (short)f2bf(a.x); r[1] = (short)f2bf(a.y);
    r[2] = (short)f2bf(a.z); r[3] = (short)f2bf(a.w);
    r[4] = (short)f2bf(b.x); r[5] = (short)f2bf(b.y);
    r[6] = (short)f2bf(b.z); r[7] = (short)f2bf(b.w);
    ((short8*)xb)[idx] = r;
  }
}

// ---------------------------------------------------------------------------
// C[M,N] = A[M,K] * B[N,K]^T, bf16 in, fp32 out.
// R4's HW-PROVEN skeleton (BM=128 x BN=256, BK=64, NBUF=3, stage-2-ahead,
// ONE {sched_barrier + vmcnt(6) + s_barrier} per K-tile), with K-SPLIT
// wave decomposition: 8 waves = 2M x 2N x 2K. Wave (wr,wc,kh) computes a
// 64x128 output sub-tile over only the kh half (K=32) of each BK=64 tile:
//   per wave per tile: 4 A-frags + 8 B-frags = 12 ds_read_b128 (was 16),
//   32 MFMA (same). Per-CU reads/tile: 96 (was 128) -> LDS service -25%.
// Epilogue: kh-pairs swap half their acc via LDS (128KB overlay on staging
// buffers, after final vmcnt(0) drain) and reduce; each wave stores its
// kept half of C.
// Swizzle (T2, R2-verified): 16B-chunk c XOR (row&7) on SOURCE and READ.
// ---------------------------------------------------------------------------
#define BM 128
#define BN 256
#define BK 64
#define NBUF 3
#define ASZ (BM * BK)          // 8192 shorts = 16KB
#define BSZ (BN * BK)          // 16384 shorts = 32KB

__global__ __launch_bounds__(512, 1) void w4a16_gemm_ks(
    const short* __restrict__ A, const short* __restrict__ B,
    float* __restrict__ C, int M, int N, int K) {
  __shared__ __attribute__((aligned(16))) char smem[NBUF * (ASZ + BSZ) * 2]; // 144KB
  short* As = (short*)smem;
  short* Bs = As + NBUF * ASZ;

  const int tid  = threadIdx.x;
  const int lane = tid & 63;
  const int wid  = tid >> 6;       // 0..7
  const int wr   = wid >> 2;       // 0..1  (M half)
  const int wc   = (wid >> 1) & 1; // 0..1  (N half)
  const int kh   = wid & 1;        // 0..1  (K half)

  const int bm = blockIdx.y * BM;
  const int bn = blockIdx.x * BN;

  f32x4 acc[4][8] = {};            // [m-frag 0..3][n-frag 0..7]

  const int fr    = lane & 15;
  const int klane = lane >> 4;
  const int xv    = fr & 7;        // read-side swizzle XOR
  const int ck    = kh * 4 + klane;   // this wave's k-chunk within the tile

  const size_t rowbytes = (size_t)K * 2;

  // ---- loop-invariant staging addresses (per-thread): only kt varies.
  size_t aoff[2];  int aldso[2];
#pragma unroll
  for (int r = 0; r < 2; ++r) {
    int u = r * 512 + tid;               // 0..1023
    int row = u >> 3, c = u & 7;
    int csrc = c ^ (row & 7);
    aoff[r]  = (size_t)(bm + row) * rowbytes + (size_t)csrc * 16;
    aldso[r] = u * 16;
  }
  size_t boff[4];  int bldso[4];
#pragma unroll
  for (int r = 0; r < 4; ++r) {
    int u = r * 512 + tid;               // 0..2047
    int row = u >> 3, c = u & 7;
    int csrc = c ^ (row & 7);
    boff[r]  = (size_t)(bn + row) * rowbytes + (size_t)csrc * 16;
    bldso[r] = u * 16;
  }

  const char* Ag = (const char*)A;
  const char* Bg = (const char*)B;

#define STAGE_A(bufbase, koff2, r)                                              \
  __builtin_amdgcn_global_load_lds(                                             \
      (const __attribute__((address_space(1))) unsigned int*)(Ag + aoff[r] + (koff2)), \
      (__attribute__((address_space(3))) unsigned int*)((char*)(bufbase) + aldso[r]),  \
      16, 0, 0)
#define STAGE_B(bufbase, koff2, r)                                              \
  __builtin_amdgcn_global_load_lds(                                             \
      (const __attribute__((address_space(1))) unsigned int*)(Bg + boff[r] + (koff2)), \
      (__attribute__((address_space(3))) unsigned int*)((char*)(bufbase) + bldso[r]),  \
      16, 0, 0)

  // swizzled fragment reads (kk fixed = this wave's kh)
  auto readA = [&](const short* Ab, int mi) -> bf16x8 {
    int row = wr * 64 + mi * 16 + fr;
    return *(const bf16x8*)((const char*)Ab + (size_t)row * 128 + ((ck ^ xv) << 4));
  };
  auto readB = [&](const short* Bb, int ni) -> bf16x8 {
    int row = wc * 128 + ni * 16 + fr;
    return *(const bf16x8*)((const char*)Bb + (size_t)row * 128 + ((ck ^ xv) << 4));
  };

  const int NT = K / BK;   // 64

  // ---- prologue: stage tiles 0 and 1; retire tile 0; publish.
  {
    char* A0 = (char*)As; char* B0 = (char*)Bs;
    char* A1 = (char*)(As + ASZ); char* B1 = (char*)(Bs + BSZ);
    STAGE_A(A0, 0, 0); STAGE_A(A0, 0, 1);
    STAGE_B(B0, 0, 0); STAGE_B(B0, 0, 1); STAGE_B(B0, 0, 2); STAGE_B(B0, 0, 3);
    size_t k2 = (size_t)BK * 2;
    STAGE_A(A1, k2, 0); STAGE_A(A1, k2, 1);
    STAGE_B(B1, k2, 0); STAGE_B(B1, k2, 1); STAGE_B(B1, k2, 2); STAGE_B(B1, k2, 3);
  }
  asm volatile("s_waitcnt vmcnt(6)");      // tile 0 complete, tile 1 in flight
  __builtin_amdgcn_s_barrier();

  int cur = 0, nxt = 2;
  for (int t = 0; t < NT; ++t) {
    const short* Ab = As + cur * ASZ;
    const short* Bb = Bs + cur * BSZ;
    char* An = (char*)(As + nxt * ASZ);
    char* Bn = (char*)(Bs + nxt * BSZ);
    const size_t koff2 = (size_t)(t + 2) * (BK * 2);
    const bool pf = (t + 2) < NT;

    bf16x8 af[4], bf[8];
#pragma unroll
    for (int mi = 0; mi < 4; ++mi) af[mi] = readA(Ab, mi);
#pragma unroll
    for (int ni = 0; ni < 8; ++ni) bf[ni] = readB(Bb, ni);

    if (pf) {
      STAGE_A(An, koff2, 0); STAGE_A(An, koff2, 1);
      STAGE_B(Bn, koff2, 0); STAGE_B(Bn, koff2, 1);
      STAGE_B(Bn, koff2, 2); STAGE_B(Bn, koff2, 3);
    }

    __builtin_amdgcn_s_setprio(1);
#pragma unroll
    for (int mi = 0; mi < 4; ++mi)
#pragma unroll
      for (int ni = 0; ni < 8; ++ni)
        acc[mi][ni] = __builtin_amdgcn_mfma_f32_16x16x32_bf16(
            af[mi], bf[ni], acc[mi][ni], 0, 0, 0);
    __builtin_amdgcn_s_setprio(0);

    if (t < NT - 1) {
      __builtin_amdgcn_sched_barrier(0);
      if (pf) asm volatile("s_waitcnt vmcnt(6)");
      else    asm volatile("s_waitcnt vmcnt(0)");
    }
    __builtin_amdgcn_s_barrier();

    cur = (cur == NBUF - 1) ? 0 : cur + 1;
    nxt = (nxt == NBUF - 1) ? 0 : nxt + 1;
  }

  // ---- epilogue: cross-kh reduction via LDS overlay, then store.
  // All staging drained (vmcnt(0) at t=NT-2); final barrier above ensures
  // every wave's last frag reads retired before we overwrite smem.
  // Region per wave-pair quadrant widx = wr*2+wc (32KB), half per kh (16KB):
  //   slot(g, ni, lane) = widx*32768 + kh*16384 + (g*8+ni)*1024 + lane*16.
  // kh=0 gives mi {2,3} (g = mi-2), keeps {0,1}; kh=1 gives {0,1} (g = mi),
  // keeps {2,3}; reader uses partner's kh^1 region at g = keep-mi & 1.
  {
    const int widx = wr * 2 + wc;
    char* epw = smem + widx * 32768 + kh * 16384 + lane * 16;
#pragma unroll
    for (int g = 0; g < 2; ++g)
#pragma unroll
      for (int ni = 0; ni < 8; ++ni) {
        int mi = kh ? g : (g + 2);
        *(f32x4*)(epw + (g * 8 + ni) * 1024) = acc[mi][ni];
      }
    asm volatile("s_waitcnt lgkmcnt(0)");
    __builtin_amdgcn_s_barrier();

    char* epr = smem + widx * 32768 + (kh ^ 1) * 16384 + lane * 16;
    const int cn = lane & 15;
    const int rb = (lane >> 4) * 4;
#pragma unroll
    for (int g = 0; g < 2; ++g)
#pragma unroll
      for (int ni = 0; ni < 8; ++ni) {
        int mi = kh ? (g + 2) : g;
        f32x4 p = *(const f32x4*)(epr + (g * 8 + ni) * 1024);
        f32x4 s = acc[mi][ni] + p;
        int m0 = bm + wr * 64 + mi * 16 + rb;
        int n0 = bn + wc * 128 + ni * 16 + cn;
#pragma unroll
        for (int r = 0; r < 4; ++r)
          C[(size_t)(m0 + r) * N + n0] = s[r];
      }
  }
}

extern "C" void kernel_launch(void* const* d_in, const int* in_sizes, int n_in,
                              void* d_out, int out_size, void* d_ws, size_t ws_size,
                              hipStream_t stream) {
  const float* x   = (const float*)d_in[0];
  const float* wsc = (const float*)d_in[1];
  const int*   wq  = (const int*)d_in[2];
  float* out = (float*)d_out;

  const int K = 4096;                 // in_features
  const int N = in_sizes[2] / K;      // out_features = 4096
  const int M = in_sizes[0] / K;      // batch*seq = 2048

  // workspace layout: W bf16 [N*K] then X bf16 [M*K]
  short* Wb = (short*)d_ws;
  short* Xb = Wb + (size_t)N * K;

  int nblkW = (N * K) / 16;           // 1048576
  int n8    = (M * K) / 8;            // 1048576
  int gridP = (nblkW >> 8) + ((n8 + 255) >> 8);
  w4a16_prep<<<gridP, 256, 0, stream>>>(wq, wsc, Wb, nblkW, x, Xb, n8);

  dim3 grid(N / BN, M / BM);
  w4a16_gemm_ks<<<grid, 512, 0, stream>>>(Xb, Wb, out, M, N, K);
}

// Round 15
// 90.825 us; speedup vs baseline: 1.4076x; 1.4076x over previous
//
#include <hip/hip_runtime.h>

typedef __bf16  bf16x8 __attribute__((ext_vector_type(8)));
typedef float   f32x4  __attribute__((ext_vector_type(4)));
typedef short   short8 __attribute__((ext_vector_type(8)));

static __device__ __forceinline__ unsigned short f2bf(float f) {
  union { float f; unsigned int u; } v; v.f = f;
  unsigned int u = v.u;
  u += 0x7fffu + ((u >> 16) & 1u);   // round-to-nearest-even
  return (unsigned short)(u >> 16);
}

// e2m1 decode: code = sign<<3 | e<<1 | m ; values {0,.5,1,1.5,2,3,4,6} * sign
static __device__ __forceinline__ float fp4_decode(int qc) {
  int e = (qc >> 1) & 3;
  float m = (float)(qc & 1);
  float mag = (e == 0) ? (0.5f * m)
                       : ((2.0f + m) * 0.5f * (float)(1 << (e - 1)));
  return (qc & 8) ? -mag : mag;
}

// Fused prep (R4-proven): blocks [0, nblkW/256) dequant W; rest convert x.
__global__ __launch_bounds__(256) void w4a16_prep(
    const int* __restrict__ wq, const float* __restrict__ wsc,
    short* __restrict__ wout, int nblkW,
    const float* __restrict__ x, short* __restrict__ xb, int n8) {
  const int nbW = nblkW >> 8;
  if ((int)blockIdx.x < nbW) {
    int idx = blockIdx.x * 256 + threadIdx.x;
    if (idx >= nblkW) return;
    float s = wsc[idx];
    const int4* qp = (const int4*)wq + (size_t)idx * 4;
    int4 q0 = qp[0], q1 = qp[1], q2 = qp[2], q3 = qp[3];
    short8 r0, r1;
    r0[0] = (short)f2bf(fp4_decode(q0.x) * s);
    r0[1] = (short)f2bf(fp4_decode(q0.y) * s);
    r0[2] = (short)f2bf(fp4_decode(q0.z) * s);
    r0[3] = (short)f2bf(fp4_decode(q0.w) * s);
    r0[4] = (short)f2bf(fp4_decode(q1.x) * s);
    r0[5] = (short)f2bf(fp4_decode(q1.y) * s);
    r0[6] = (short)f2bf(fp4_decode(q1.z) * s);
    r0[7] = (short)f2bf(fp4_decode(q1.w) * s);
    r1[0] = (short)f2bf(fp4_decode(q2.x) * s);
    r1[1] = (short)f2bf(fp4_decode(q2.y) * s);
    r1[2] = (short)f2bf(fp4_decode(q2.z) * s);
    r1[3] = (short)f2bf(fp4_decode(q2.w) * s);
    r1[4] = (short)f2bf(fp4_decode(q3.x) * s);
    r1[5] = (short)f2bf(fp4_decode(q3.y) * s);
    r1[6] = (short)f2bf(fp4_decode(q3.z) * s);
    r1[7] = (short)f2bf(fp4_decode(q3.w) * s);
    short8* op = (short8*)wout + (size_t)idx * 2;
    op[0] = r0;
    op[1] = r1;
  } else {
    int idx = (blockIdx.x - nbW) * 256 + threadIdx.x;
    if (idx >= n8) return;
    const float4* xp = (const float4*)x + (size_t)idx * 2;
    float4 a = xp[0], b = xp[1];
    short8 r;
    r[0] = (short)f2bf(a.x); r[1] = (short)f2bf(a.y);
    r[2] = (short)f2bf(a.z); r[3] = (short)f2bf(a.w);
    r[4] = (short)f2bf(b.x); r[5] = (short)f2bf(b.y);
    r[6] = (short)f2bf(b.z); r[7] = (short)f2bf(b.w);
    ((short8*)xb)[idx] = r;
  }
}

// ---------------------------------------------------------------------------
// C[M,N] = A[M,K] * B[N,K]^T, bf16 in, fp32 out.
// R4's HW-PROVEN skeleton + K-SPLIT waves (R14-verified correct; R14's
// regression was rule-#20 scratch spill from runtime acc indexing in the
// epilogue — fixed here with kh-uniform static branches).
// 8 waves = 2M x 2N x 2K; wave (wr,wc,kh) computes 64x128 outputs over the
// kh half (K=32) of each BK=64 tile: 12 ds_read_b128/tile/wave (was 16).
// Epilogue: kh-pairs swap half their acc via LDS overlay (after final
// drain), reduce, store — ALL acc indices compile-time.
// Swizzle (T2): 16B-chunk c XOR (row&7) on SOURCE and READ.
// ---------------------------------------------------------------------------
#define BM 128
#define BN 256
#define BK 64
#define NBUF 3
#define ASZ (BM * BK)          // 8192 shorts = 16KB
#define BSZ (BN * BK)          // 16384 shorts = 32KB

__global__ __launch_bounds__(512, 1) void w4a16_gemm_ks2(
    const short* __restrict__ A, const short* __restrict__ B,
    float* __restrict__ C, int M, int N, int K) {
  __shared__ __attribute__((aligned(16))) char smem[NBUF * (ASZ + BSZ) * 2]; // 144KB
  short* As = (short*)smem;
  short* Bs = As + NBUF * ASZ;

  const int tid  = threadIdx.x;
  const int lane = tid & 63;
  const int wid  = tid >> 6;       // 0..7
  const int wr   = wid >> 2;       // 0..1  (M half)
  const int wc   = (wid >> 1) & 1; // 0..1  (N half)
  const int kh   = wid & 1;        // 0..1  (K half)

  const int bm = blockIdx.y * BM;
  const int bn = blockIdx.x * BN;

  f32x4 acc[4][8] = {};            // [m-frag 0..3][n-frag 0..7] — static idx ONLY

  const int fr    = lane & 15;
  const int klane = lane >> 4;
  const int xv    = fr & 7;        // read-side swizzle XOR
  const int ck    = kh * 4 + klane;   // this wave's k-chunk within the tile

  const size_t rowbytes = (size_t)K * 2;

  // ---- loop-invariant staging addresses (per-thread): only kt varies.
  size_t aoff[2];  int aldso[2];
#pragma unroll
  for (int r = 0; r < 2; ++r) {
    int u = r * 512 + tid;               // 0..1023
    int row = u >> 3, c = u & 7;
    int csrc = c ^ (row & 7);
    aoff[r]  = (size_t)(bm + row) * rowbytes + (size_t)csrc * 16;
    aldso[r] = u * 16;
  }
  size_t boff[4];  int bldso[4];
#pragma unroll
  for (int r = 0; r < 4; ++r) {
    int u = r * 512 + tid;               // 0..2047
    int row = u >> 3, c = u & 7;
    int csrc = c ^ (row & 7);
    boff[r]  = (size_t)(bn + row) * rowbytes + (size_t)csrc * 16;
    bldso[r] = u * 16;
  }

  const char* Ag = (const char*)A;
  const char* Bg = (const char*)B;

#define STAGE_A(bufbase, koff2, r)                                              \
  __builtin_amdgcn_global_load_lds(                                             \
      (const __attribute__((address_space(1))) unsigned int*)(Ag + aoff[r] + (koff2)), \
      (__attribute__((address_space(3))) unsigned int*)((char*)(bufbase) + aldso[r]),  \
      16, 0, 0)
#define STAGE_B(bufbase, koff2, r)                                              \
  __builtin_amdgcn_global_load_lds(                                             \
      (const __attribute__((address_space(1))) unsigned int*)(Bg + boff[r] + (koff2)), \
      (__attribute__((address_space(3))) unsigned int*)((char*)(bufbase) + bldso[r]),  \
      16, 0, 0)

  // swizzled fragment reads (k fixed = this wave's kh half)
  auto readA = [&](const short* Ab, int mi) -> bf16x8 {
    int row = wr * 64 + mi * 16 + fr;
    return *(const bf16x8*)((const char*)Ab + (size_t)row * 128 + ((ck ^ xv) << 4));
  };
  auto readB = [&](const short* Bb, int ni) -> bf16x8 {
    int row = wc * 128 + ni * 16 + fr;
    return *(const bf16x8*)((const char*)Bb + (size_t)row * 128 + ((ck ^ xv) << 4));
  };

  const int NT = K / BK;   // 64

  // ---- prologue: stage tiles 0 and 1; retire tile 0; publish.
  {
    char* A0 = (char*)As; char* B0 = (char*)Bs;
    char* A1 = (char*)(As + ASZ); char* B1 = (char*)(Bs + BSZ);
    STAGE_A(A0, 0, 0); STAGE_A(A0, 0, 1);
    STAGE_B(B0, 0, 0); STAGE_B(B0, 0, 1); STAGE_B(B0, 0, 2); STAGE_B(B0, 0, 3);
    size_t k2 = (size_t)BK * 2;
    STAGE_A(A1, k2, 0); STAGE_A(A1, k2, 1);
    STAGE_B(B1, k2, 0); STAGE_B(B1, k2, 1); STAGE_B(B1, k2, 2); STAGE_B(B1, k2, 3);
  }
  asm volatile("s_waitcnt vmcnt(6)");      // tile 0 complete, tile 1 in flight
  __builtin_amdgcn_s_barrier();

  int cur = 0, nxt = 2;
  for (int t = 0; t < NT; ++t) {
    const short* Ab = As + cur * ASZ;
    const short* Bb = Bs + cur * BSZ;
    char* An = (char*)(As + nxt * ASZ);
    char* Bn = (char*)(Bs + nxt * BSZ);
    const size_t koff2 = (size_t)(t + 2) * (BK * 2);
    const bool pf = (t + 2) < NT;

    bf16x8 af[4], bf[8];
#pragma unroll
    for (int mi = 0; mi < 4; ++mi) af[mi] = readA(Ab, mi);
#pragma unroll
    for (int ni = 0; ni < 8; ++ni) bf[ni] = readB(Bb, ni);

    if (pf) {
      STAGE_A(An, koff2, 0); STAGE_A(An, koff2, 1);
      STAGE_B(Bn, koff2, 0); STAGE_B(Bn, koff2, 1);
      STAGE_B(Bn, koff2, 2); STAGE_B(Bn, koff2, 3);
    }

    __builtin_amdgcn_s_setprio(1);
#pragma unroll
    for (int mi = 0; mi < 4; ++mi)
#pragma unroll
      for (int ni = 0; ni < 8; ++ni)
        acc[mi][ni] = __builtin_amdgcn_mfma_f32_16x16x32_bf16(
            af[mi], bf[ni], acc[mi][ni], 0, 0, 0);
    __builtin_amdgcn_s_setprio(0);

    if (t < NT - 1) {
      __builtin_amdgcn_sched_barrier(0);
      if (pf) asm volatile("s_waitcnt vmcnt(6)");
      else    asm volatile("s_waitcnt vmcnt(0)");
    }
    __builtin_amdgcn_s_barrier();

    cur = (cur == NBUF - 1) ? 0 : cur + 1;
    nxt = (nxt == NBUF - 1) ? 0 : nxt + 1;
  }

  // ---- epilogue: cross-kh reduction via LDS overlay (static acc idx only).
  // Region per quadrant widx = wr*2+wc (32KB), half per kh (16KB):
  //   slot(s, lane) = widx*32768 + kh*16384 + s*1024 + lane*16, s = g*8+ni.
  // kh=0 ships acc[2],acc[3] (g=0,1), keeps acc[0],acc[1];
  // kh=1 ships acc[0],acc[1] (g=0,1), keeps acc[2],acc[3].
  {
    const int widx = wr * 2 + wc;
    char* epw = smem + widx * 32768 + kh * 16384 + lane * 16;
    if (kh == 0) {
#pragma unroll
      for (int ni = 0; ni < 8; ++ni) *(f32x4*)(epw + ni * 1024)        = acc[2][ni];
#pragma unroll
      for (int ni = 0; ni < 8; ++ni) *(f32x4*)(epw + (8 + ni) * 1024)  = acc[3][ni];
    } else {
#pragma unroll
      for (int ni = 0; ni < 8; ++ni) *(f32x4*)(epw + ni * 1024)        = acc[0][ni];
#pragma unroll
      for (int ni = 0; ni < 8; ++ni) *(f32x4*)(epw + (8 + ni) * 1024)  = acc[1][ni];
    }
    asm volatile("s_waitcnt lgkmcnt(0)");
    __builtin_amdgcn_s_barrier();

    char* epr = smem + widx * 32768 + (kh ^ 1) * 16384 + lane * 16;
    const int cn = lane & 15;
    const int rb = (lane >> 4) * 4;

#define STORE_ROW(mi_, ni_, sv_)                                                \
    do {                                                                        \
      int m0 = bm + wr * 64 + (mi_) * 16 + rb;                                  \
      int n0 = bn + wc * 128 + (ni_) * 16 + cn;                                 \
      _Pragma("unroll") for (int r = 0; r < 4; ++r)                             \
        C[(size_t)(m0 + r) * N + n0] = (sv_)[r];                                \
    } while (0)

    if (kh == 0) {
      // partner (kh=1) shipped acc[0],acc[1] at slots ni, 8+ni
#pragma unroll
      for (int ni = 0; ni < 8; ++ni) {
        f32x4 p = *(const f32x4*)(epr + ni * 1024);
        f32x4 s = acc[0][ni] + p;
        STORE_ROW(0, ni, s);
      }
#pragma unroll
      for (int ni = 0; ni < 8; ++ni) {
        f32x4 p = *(const f32x4*)(epr + (8 + ni) * 1024);
        f32x4 s = acc[1][ni] + p;
        STORE_ROW(1, ni, s);
      }
    } else {
      // partner (kh=0) shipped acc[2],acc[3] at slots ni, 8+ni
#pragma unroll
      for (int ni = 0; ni < 8; ++ni) {
        f32x4 p = *(const f32x4*)(epr + ni * 1024);
        f32x4 s = acc[2][ni] + p;
        STORE_ROW(2, ni, s);
      }
#pragma unroll
      for (int ni = 0; ni < 8; ++ni) {
        f32x4 p = *(const f32x4*)(epr + (8 + ni) * 1024);
        f32x4 s = acc[3][ni] + p;
        STORE_ROW(3, ni, s);
      }
    }
  }
}

extern "C" void kernel_launch(void* const* d_in, const int* in_sizes, int n_in,
                              void* d_out, int out_size, void* d_ws, size_t ws_size,
                              hipStream_t stream) {
  const float* x   = (const float*)d_in[0];
  const float* wsc = (const float*)d_in[1];
  const int*   wq  = (const int*)d_in[2];
  float* out = (float*)d_out;

  const int K = 4096;                 // in_features
  const int N = in_sizes[2] / K;      // out_features = 4096
  const int M = in_sizes[0] / K;      // batch*seq = 2048

  // workspace layout: W bf16 [N*K] then X bf16 [M*K]
  short* Wb = (short*)d_ws;
  short* Xb = Wb + (size_t)N * K;

  int nblkW = (N * K) / 16;           // 1048576
  int n8    = (M * K) / 8;            // 1048576
  int gridP = (nblkW >> 8) + ((n8 + 255) >> 8);
  w4a16_prep<<<gridP, 256, 0, stream>>>(wq, wsc, Wb, nblkW, x, Xb, n8);

  dim3 grid(N / BN, M / BM);
  w4a16_gemm_ks2<<<grid, 512, 0, stream>>>(Xb, Wb, out, M, N, K);
}